// Round 1
// baseline (1009.849 us; speedup 1.0000x reference)
//
#include <hip/hip_runtime.h>

// ---------------------------------------------------------------------------
// DeepProteinClassifier: x[32,1024,960] fp32, mask[32,1024] i32 ->
//   QKV proj -> attention -> +x, LN -> masked mean pool -> MLP -> [32,10] f32
// Strategy: bf16 MFMA (16x16x32) for projections / scores / PV; fp32 epilogues.
// ---------------------------------------------------------------------------

#define DEVINL __device__ __forceinline__

typedef __attribute__((ext_vector_type(8))) short bf16x8;
typedef __attribute__((ext_vector_type(4))) float f32x4;
typedef __attribute__((ext_vector_type(4))) unsigned short u16x4;

DEVINL unsigned short f2bf(float f) {
  unsigned int u = __float_as_uint(f);
  u += 0x7FFFu + ((u >> 16) & 1u);       // round-to-nearest-even
  return (unsigned short)(u >> 16);
}

DEVINL void gload_lds16(const void* g, void* l) {
  // async global->LDS, 16B per lane; LDS dest = wave-uniform base + lane*16
  __builtin_amdgcn_global_load_lds((const __attribute__((address_space(1))) unsigned int*)g,
                                   (__attribute__((address_space(3))) unsigned int*)l,
                                   16, 0, 0);
}

#define MFMA16(a, b, c) __builtin_amdgcn_mfma_f32_16x16x32_bf16((a), (b), (c), 0, 0, 0)

// ---------------------------------------------------------------------------
// Cast the three projection weight matrices [960x960] f32 -> bf16.
// grid (900,1,3), block 256, 4 elems/thread.
// ---------------------------------------------------------------------------
__global__ __launch_bounds__(256) void cast_w(
    const float* __restrict__ Wq, const float* __restrict__ Wk, const float* __restrict__ Wv,
    unsigned short* __restrict__ Wqb, unsigned short* __restrict__ Wkb,
    unsigned short* __restrict__ Wvb) {
  const int z = blockIdx.z;
  const float* src = (z == 0) ? Wq : (z == 1) ? Wk : Wv;
  unsigned short* dst = (z == 0) ? Wqb : (z == 1) ? Wkb : Wvb;
  const int i = (blockIdx.x * 256 + threadIdx.x) * 4;
  f32x4 v = *(const f32x4*)(src + i);
  u16x4 o;
  o[0] = f2bf(v[0]); o[1] = f2bf(v[1]); o[2] = f2bf(v[2]); o[3] = f2bf(v[3]);
  *(u16x4*)(dst + i) = o;
}

// ---------------------------------------------------------------------------
// NT GEMM, 128x128 tile, BK=32, 4 waves (2x2), each wave 64x64 out.
// A_F32: A is fp32, reg-staged with cast to bf16. else bf16 via global_load_lds.
// OUT_BF16: out = bf16( (acc+bias[col]) * scale ).  else raw fp32.
// A: [M x lda] K-contig.  B: [Nrows x ldb] K-contig (row n = out col n).
// Requires: M % 128 == 0; B rows allocated up to gridDim.y*128 (garbage rows
// only feed out-cols >= ncols which are never stored).
// ---------------------------------------------------------------------------
template <int A_F32, int OUT_BF16>
__global__ __launch_bounds__(256) void gemm_nt(
    const void* __restrict__ Ap, const unsigned short* __restrict__ Bp,
    const float* __restrict__ bias, float scale, void* __restrict__ Op,
    int lda, int ldb, int ldo, int ncols, int ksteps,
    size_t aStride, size_t bStride, size_t oStride) {
  __shared__ unsigned short As[128 * 32];
  __shared__ unsigned short Bs[128 * 32];
  const int t = threadIdx.x, l = t & 63, w = t >> 6;
  const int wr = w >> 1, wc = w & 1;
  const int m0 = blockIdx.x * 128, n0 = blockIdx.y * 128;
  const int bz = blockIdx.z;
  const unsigned short* B = Bp + (size_t)bz * bStride;

  f32x4 acc[4][4] = {};

  for (int kk = 0; kk < ksteps; ++kk) {
    const int d0 = kk * 32;
    __syncthreads();
    {  // stage B: two 1KB chunks per wave (16 rows x 64B each), linear LDS
      const int row = 32 * w + (l >> 2);
      const unsigned short* g = B + (size_t)(n0 + row) * ldb + d0 + (l & 3) * 8;
      gload_lds16(g, (char*)Bs + (size_t)(32 * w) * 64);
      gload_lds16(g + (size_t)16 * ldb, (char*)Bs + (size_t)(32 * w + 16) * 64);
    }
    if (A_F32) {  // stage A: fp32 -> bf16, 16 elems/thread
      const float* A = (const float*)Ap + (size_t)bz * aStride;
      const int row = t >> 1, cb = (t & 1) * 16;
      const float* g = A + (size_t)(m0 + row) * lda + d0 + cb;
      f32x4 v0 = *(const f32x4*)(g);
      f32x4 v1 = *(const f32x4*)(g + 4);
      f32x4 v2 = *(const f32x4*)(g + 8);
      f32x4 v3 = *(const f32x4*)(g + 12);
      bf16x8 o0, o1;
      o0[0] = (short)f2bf(v0[0]); o0[1] = (short)f2bf(v0[1]);
      o0[2] = (short)f2bf(v0[2]); o0[3] = (short)f2bf(v0[3]);
      o0[4] = (short)f2bf(v1[0]); o0[5] = (short)f2bf(v1[1]);
      o0[6] = (short)f2bf(v1[2]); o0[7] = (short)f2bf(v1[3]);
      o1[0] = (short)f2bf(v2[0]); o1[1] = (short)f2bf(v2[1]);
      o1[2] = (short)f2bf(v2[2]); o1[3] = (short)f2bf(v2[3]);
      o1[4] = (short)f2bf(v3[0]); o1[5] = (short)f2bf(v3[1]);
      o1[6] = (short)f2bf(v3[2]); o1[7] = (short)f2bf(v3[3]);
      *(bf16x8*)(As + (size_t)row * 32 + cb) = o0;
      *(bf16x8*)(As + (size_t)row * 32 + cb + 8) = o1;
    } else {
      const unsigned short* A = (const unsigned short*)Ap + (size_t)bz * aStride;
      const int row = 32 * w + (l >> 2);
      const unsigned short* g = A + (size_t)(m0 + row) * lda + d0 + (l & 3) * 8;
      gload_lds16(g, (char*)As + (size_t)(32 * w) * 64);
      gload_lds16(g + (size_t)16 * lda, (char*)As + (size_t)(32 * w + 16) * 64);
    }
    __syncthreads();
    bf16x8 aF[4], bF[4];
#pragma unroll
    for (int i = 0; i < 4; ++i)
      aF[i] = *(const bf16x8*)(As + (size_t)(64 * wr + 16 * i + (l & 15)) * 32 + (l >> 4) * 8);
#pragma unroll
    for (int j = 0; j < 4; ++j)
      bF[j] = *(const bf16x8*)(Bs + (size_t)(64 * wc + 16 * j + (l & 15)) * 32 + (l >> 4) * 8);
#pragma unroll
    for (int i = 0; i < 4; ++i)
#pragma unroll
      for (int j = 0; j < 4; ++j) acc[i][j] = MFMA16(aF[i], bF[j], acc[i][j]);
  }

  // epilogue: C/D layout col = lane&15, row = (lane>>4)*4 + reg
#pragma unroll
  for (int j = 0; j < 4; ++j) {
    const int col = n0 + 64 * wc + 16 * j + (l & 15);
    if (col < ncols) {
      float bv = 0.0f;
      if (OUT_BF16) bv = bias[col];
#pragma unroll
      for (int i = 0; i < 4; ++i) {
#pragma unroll
        for (int r = 0; r < 4; ++r) {
          const int row = m0 + 64 * wr + 16 * i + 4 * (l >> 4) + r;
          const float v = acc[i][j][r];
          if (OUT_BF16) {
            ((unsigned short*)Op)[(size_t)bz * oStride + (size_t)row * ldo + col] =
                f2bf((v + bv) * scale);
          } else {
            ((float*)Op)[(size_t)bz * oStride + (size_t)row * ldo + col] = v;
          }
        }
      }
    }
  }
}

// ---------------------------------------------------------------------------
// V [b,s,960] bf16 -> Vt [b, d(1024 alloc, 960 used), s:1024] bf16.
// 64x64 tiles, 4x4 micro-transpose in registers. grid (15,16,32) block 256.
// ---------------------------------------------------------------------------
__global__ __launch_bounds__(256) void transpose_v(
    const unsigned short* __restrict__ Vb, unsigned short* __restrict__ Vt) {
  const int t = threadIdx.x, tx = t & 15, ty = t >> 4;
  const int d0 = blockIdx.x * 64, s0 = blockIdx.y * 64, b = blockIdx.z;
  const size_t ib = (size_t)b * 1024 * 960;
  const size_t ob = (size_t)b * 1024 * 1024;
  u16x4 r[4];
#pragma unroll
  for (int i = 0; i < 4; ++i)
    r[i] = *(const u16x4*)(Vb + ib + (size_t)(s0 + ty * 4 + i) * 960 + d0 + tx * 4);
#pragma unroll
  for (int j = 0; j < 4; ++j) {
    u16x4 o;
    o[0] = r[0][j]; o[1] = r[1][j]; o[2] = r[2][j]; o[3] = r[3][j];
    *(u16x4*)(Vt + ob + (size_t)(d0 + tx * 4 + j) * 1024 + s0 + ty * 4) = o;
  }
}

// ---------------------------------------------------------------------------
// Fused scores + masked softmax. Block = (b, 32 q-rows) x full 1024 k.
// 8 waves; wave w owns k-cols [128w,128w+128). Q tile + K d-slab in LDS
// (padded rows to break the 1920B/64B-stride bank conflicts).
// Scale 1/sqrt(960) is pre-folded into Q. P stored normalized bf16.
// ---------------------------------------------------------------------------
__global__ __launch_bounds__(512) void attn_softmax(
    const unsigned short* __restrict__ Qb, const unsigned short* __restrict__ Kb,
    const int* __restrict__ mask, unsigned short* __restrict__ P) {
  __shared__ unsigned short Qs[32 * 968];   // pad 960->968 (stride 1936B)
  __shared__ unsigned short Ks[1024 * 40];  // pad 32->40  (stride 80B)
  __shared__ float red[2][8][32];
  const int t = threadIdx.x, l = t & 63, w = t >> 6;
  const int b = blockIdx.y, q0 = blockIdx.x * 32;
  const int lq = l & 15, lh = l >> 4;

  {  // stage Q tile 32x960
    const size_t qbase = ((size_t)b * 1024 + q0) * 960;
    for (int off = t * 8; off < 32 * 960; off += 512 * 8) {
      const int row = off / 960, col = off % 960;
      *(bf16x8*)(Qs + row * 968 + col) = *(const bf16x8*)(Qb + qbase + (size_t)row * 960 + col);
    }
  }

  f32x4 acc[2][8] = {};
  const size_t kbase = (size_t)b * 1024 * 960;
  const int sub = t & 3, rb = t >> 2;
  for (int kk = 0; kk < 30; ++kk) {
    const int d0 = kk * 32;
    __syncthreads();
#pragma unroll
    for (int r0 = 0; r0 < 1024; r0 += 128) {  // stage K[0:1024, d0:d0+32]
      const int row = r0 + rb;
      *(bf16x8*)(Ks + row * 40 + sub * 8) =
          *(const bf16x8*)(Kb + kbase + (size_t)row * 960 + d0 + sub * 8);
    }
    __syncthreads();
    bf16x8 aF[2], bF[8];
#pragma unroll
    for (int i = 0; i < 2; ++i)
      aF[i] = *(const bf16x8*)(Qs + (16 * i + lq) * 968 + d0 + lh * 8);
#pragma unroll
    for (int j = 0; j < 8; ++j)
      bF[j] = *(const bf16x8*)(Ks + (128 * w + 16 * j + lq) * 40 + lh * 8);
#pragma unroll
    for (int i = 0; i < 2; ++i)
#pragma unroll
      for (int j = 0; j < 8; ++j) acc[i][j] = MFMA16(aF[i], bF[j], acc[i][j]);
  }

  // mask: col k masked -> -1e9 (matches reference jnp.where before softmax)
#pragma unroll
  for (int j = 0; j < 8; ++j) {
    const int k = 128 * w + 16 * j + lq;
    if (mask[b * 1024 + k] == 0) {
#pragma unroll
      for (int i = 0; i < 2; ++i)
#pragma unroll
        for (int r = 0; r < 4; ++r) acc[i][j][r] = -1e9f;
    }
  }

  // row max: in-lane over j, shuffle over the 16 col-lanes, LDS over 8 waves
  float rmax[2][4];
#pragma unroll
  for (int i = 0; i < 2; ++i)
#pragma unroll
    for (int r = 0; r < 4; ++r) {
      float m = acc[i][0][r];
#pragma unroll
      for (int j = 1; j < 8; ++j) m = fmaxf(m, acc[i][j][r]);
      m = fmaxf(m, __shfl_xor(m, 1));
      m = fmaxf(m, __shfl_xor(m, 2));
      m = fmaxf(m, __shfl_xor(m, 4));
      m = fmaxf(m, __shfl_xor(m, 8));
      rmax[i][r] = m;
    }
  if (lq == 0) {
#pragma unroll
    for (int i = 0; i < 2; ++i)
#pragma unroll
      for (int r = 0; r < 4; ++r) red[0][w][16 * i + 4 * lh + r] = rmax[i][r];
  }
  __syncthreads();
#pragma unroll
  for (int i = 0; i < 2; ++i)
#pragma unroll
    for (int r = 0; r < 4; ++r) {
      const int rowi = 16 * i + 4 * lh + r;
      float m = red[0][0][rowi];
#pragma unroll
      for (int w2 = 1; w2 < 8; ++w2) m = fmaxf(m, red[0][w2][rowi]);
      rmax[i][r] = m;
    }

  // exp + row sum
  float rsum[2][4];
#pragma unroll
  for (int i = 0; i < 2; ++i)
#pragma unroll
    for (int r = 0; r < 4; ++r) {
      float s = 0.f;
#pragma unroll
      for (int j = 0; j < 8; ++j) {
        const float e = __expf(acc[i][j][r] - rmax[i][r]);
        acc[i][j][r] = e;
        s += e;
      }
      s += __shfl_xor(s, 1); s += __shfl_xor(s, 2);
      s += __shfl_xor(s, 4); s += __shfl_xor(s, 8);
      rsum[i][r] = s;
    }
  if (lq == 0) {
#pragma unroll
    for (int i = 0; i < 2; ++i)
#pragma unroll
      for (int r = 0; r < 4; ++r) red[1][w][16 * i + 4 * lh + r] = rsum[i][r];
  }
  __syncthreads();

  const size_t pb = ((size_t)b << 20) + (size_t)q0 * 1024;
#pragma unroll
  for (int i = 0; i < 2; ++i)
#pragma unroll
    for (int r = 0; r < 4; ++r) {
      const int rowi = 16 * i + 4 * lh + r;
      float s = 0.f;
#pragma unroll
      for (int w2 = 0; w2 < 8; ++w2) s += red[1][w2][rowi];
      const float inv = 1.0f / s;
#pragma unroll
      for (int j = 0; j < 8; ++j) {
        const int col = 128 * w + 16 * j + lq;
        P[pb + (size_t)rowi * 1024 + col] = f2bf(acc[i][j][r] * inv);
      }
    }
}

// ---------------------------------------------------------------------------
// h = ctx + x; LayerNorm(h)*g+b; pooled[b,d] += y for masked rows (atomics).
// grid (32 s-chunks, 32 b), block 256 (4 waves x 8 rows each, wave-per-row).
// ---------------------------------------------------------------------------
__global__ __launch_bounds__(256) void ln_pool(
    const float* __restrict__ ctx, const float* __restrict__ x, const int* __restrict__ mask,
    const float* __restrict__ g, const float* __restrict__ bta, float* __restrict__ pooled) {
  const int b = blockIdx.y, chunk = blockIdx.x;
  const int w = threadIdx.x >> 6, l = threadIdx.x & 63;
  f32x4 gc[4], bc[4];
#pragma unroll
  for (int c = 0; c < 4; ++c) {
    const int i4 = c * 64 + l;
    if (i4 < 240) {
      gc[c] = *(const f32x4*)(g + i4 * 4);
      bc[c] = *(const f32x4*)(bta + i4 * 4);
    }
  }
  f32x4 accp[4] = {};
  for (int rr = 0; rr < 8; ++rr) {
    const int s = chunk * 32 + w * 8 + rr;
    if (mask[b * 1024 + s] == 0) continue;  // wave-uniform branch
    const size_t base = ((size_t)b * 1024 + s) * 960;
    f32x4 h[4];
    float part = 0.f;
#pragma unroll
    for (int c = 0; c < 4; ++c) {
      const int i4 = c * 64 + l;
      if (i4 < 240) {
        f32x4 cv = *(const f32x4*)(ctx + base + (size_t)i4 * 4);
        f32x4 xv = *(const f32x4*)(x + base + (size_t)i4 * 4);
        h[c] = cv + xv;
        part += h[c][0] + h[c][1] + h[c][2] + h[c][3];
      } else {
        h[c] = 0;
      }
    }
#pragma unroll
    for (int o = 1; o < 64; o <<= 1) part += __shfl_xor(part, o);
    const float mu = part * (1.0f / 960.0f);
    float p2 = 0.f;
#pragma unroll
    for (int c = 0; c < 4; ++c) {
      if (c * 64 + l < 240) {
#pragma unroll
        for (int k2 = 0; k2 < 4; ++k2) {
          const float d = h[c][k2] - mu;
          p2 += d * d;
        }
      }
    }
#pragma unroll
    for (int o = 1; o < 64; o <<= 1) p2 += __shfl_xor(p2, o);
    const float rs = rsqrtf(p2 * (1.0f / 960.0f) + 1e-5f);
#pragma unroll
    for (int c = 0; c < 4; ++c) {
      if (c * 64 + l < 240) {
#pragma unroll
        for (int k2 = 0; k2 < 4; ++k2)
          accp[c][k2] += (h[c][k2] - mu) * rs * gc[c][k2] + bc[c][k2];
      }
    }
  }
#pragma unroll
  for (int c = 0; c < 4; ++c) {
    const int i4 = c * 64 + l;
    if (i4 < 240) {
#pragma unroll
      for (int k2 = 0; k2 < 4; ++k2) atomicAdd(&pooled[b * 960 + i4 * 4 + k2], accp[c][k2]);
    }
  }
}

// ---------------------------------------------------------------------------
// pooled/count -> 960-512-256-128-10 MLP, fp32. One block per batch row.
// ---------------------------------------------------------------------------
__global__ __launch_bounds__(256) void mlp_head(
    const float* __restrict__ pooled, const int* __restrict__ mask,
    const float* __restrict__ W1, const float* __restrict__ b1,
    const float* __restrict__ W2, const float* __restrict__ b2,
    const float* __restrict__ W3, const float* __restrict__ b3,
    const float* __restrict__ W4, const float* __restrict__ b4, float* __restrict__ out) {
  __shared__ float h0[960], h1[512], h2[256], h3[128];
  __shared__ float csh[4];
  const int b = blockIdx.x, t = threadIdx.x;
  int cnt = 0;
  for (int s = t; s < 1024; s += 256) cnt += (mask[b * 1024 + s] != 0) ? 1 : 0;
#pragma unroll
  for (int o = 1; o < 64; o <<= 1) cnt += __shfl_xor(cnt, o);
  if ((t & 63) == 0) csh[t >> 6] = (float)cnt;
  __syncthreads();
  const float inv = 1.0f / fmaxf(csh[0] + csh[1] + csh[2] + csh[3], 1e-9f);
  for (int d = t; d < 960; d += 256) h0[d] = pooled[b * 960 + d] * inv;
  __syncthreads();
  for (int o = t; o < 512; o += 256) {
    float a = b1[o];
    const float* wr = W1 + (size_t)o * 960;
    for (int k = 0; k < 960; k += 4) {
      f32x4 wv = *(const f32x4*)(wr + k);
      f32x4 hv = *(const f32x4*)(h0 + k);
      a += wv[0] * hv[0] + wv[1] * hv[1] + wv[2] * hv[2] + wv[3] * hv[3];
    }
    h1[o] = fmaxf(a, 0.f);
  }
  __syncthreads();
  {
    float a = b2[t];
    const float* wr = W2 + (size_t)t * 512;
    for (int k = 0; k < 512; k += 4) {
      f32x4 wv = *(const f32x4*)(wr + k);
      f32x4 hv = *(const f32x4*)(h1 + k);
      a += wv[0] * hv[0] + wv[1] * hv[1] + wv[2] * hv[2] + wv[3] * hv[3];
    }
    h2[t] = fmaxf(a, 0.f);
  }
  __syncthreads();
  if (t < 128) {
    float a = b3[t];
    const float* wr = W3 + (size_t)t * 256;
    for (int k = 0; k < 256; k += 4) {
      f32x4 wv = *(const f32x4*)(wr + k);
      f32x4 hv = *(const f32x4*)(h2 + k);
      a += wv[0] * hv[0] + wv[1] * hv[1] + wv[2] * hv[2] + wv[3] * hv[3];
    }
    h3[t] = fmaxf(a, 0.f);
  }
  __syncthreads();
  if (t < 10) {
    float a = b4[t];
    const float* wr = W4 + (size_t)t * 128;
    for (int k = 0; k < 128; ++k) a += wr[k] * h3[k];
    out[b * 10 + t] = a;
  }
}

// ---------------------------------------------------------------------------
// Workspace layout (bytes):
//   [0,           67108864)  P  bf16 [32][1024][1024]   (first holds Vb bf16)
//   [67108864,   134217728)  Vt bf16 [32][1024][1024]   (d rows 960..1023 garbage)
//   [134217728,  260046848)  Qb+Kb bf16 (62914560 each) -> reused as ctx f32
//   [260046848,  260169728)  pooled f32 [32][960]
//   [260169728,  266461184)  Wq/Wk/Wv bf16, 2MB stride (rows 960..1023 garbage)
// Total ~254 MiB.
// ---------------------------------------------------------------------------
extern "C" void kernel_launch(void* const* d_in, const int* in_sizes, int n_in,
                              void* d_out, int out_size, void* d_ws, size_t ws_size,
                              hipStream_t stream) {
  (void)in_sizes; (void)n_in; (void)out_size; (void)ws_size;
  const float* x    = (const float*)d_in[0];
  const int*   mask = (const int*)d_in[1];
  const float* Wq   = (const float*)d_in[2];
  const float* bq   = (const float*)d_in[3];
  const float* Wk   = (const float*)d_in[4];
  const float* bk   = (const float*)d_in[5];
  const float* Wv   = (const float*)d_in[6];
  const float* bv   = (const float*)d_in[7];
  const float* lng  = (const float*)d_in[8];
  const float* lnb  = (const float*)d_in[9];
  const float* W1   = (const float*)d_in[10];
  const float* b1   = (const float*)d_in[11];
  const float* W2   = (const float*)d_in[12];
  const float* b2   = (const float*)d_in[13];
  const float* W3   = (const float*)d_in[14];
  const float* b3   = (const float*)d_in[15];
  const float* W4   = (const float*)d_in[16];
  const float* b4   = (const float*)d_in[17];
  float* out = (float*)d_out;

  char* ws = (char*)d_ws;
  unsigned short* P      = (unsigned short*)(ws);
  unsigned short* Vb     = P;  // Vb lives in P's region until transposed
  unsigned short* Vt     = (unsigned short*)(ws + 67108864);
  unsigned short* Qb     = (unsigned short*)(ws + 134217728);
  unsigned short* Kb     = (unsigned short*)(ws + 197132288);
  float*          ctx    = (float*)(ws + 134217728);  // reuses Qb/Kb after attn
  float*          pooled = (float*)(ws + 260046848);
  unsigned short* Wqb    = (unsigned short*)(ws + 260169728);
  unsigned short* Wkb    = Wqb + 1048576;
  unsigned short* Wvb    = Wkb + 1048576;

  const float scaleQ = 0.0322748612183951f;  // 1/sqrt(960)

  cast_w<<<dim3(900, 1, 3), 256, 0, stream>>>(Wq, Wk, Wv, Wqb, Wkb, Wvb);

  // projections: [32768x960] = x[32768x960] . W^T[960x960]  (+bias; Q scaled)
  gemm_nt<1, 1><<<dim3(256, 8, 1), 256, 0, stream>>>(
      x, Wqb, bq, scaleQ, Qb, 960, 960, 960, 960, 30, 0, 0, 0);
  gemm_nt<1, 1><<<dim3(256, 8, 1), 256, 0, stream>>>(
      x, Wkb, bk, 1.0f, Kb, 960, 960, 960, 960, 30, 0, 0, 0);
  gemm_nt<1, 1><<<dim3(256, 8, 1), 256, 0, stream>>>(
      x, Wvb, bv, 1.0f, Vb, 960, 960, 960, 960, 30, 0, 0, 0);

  transpose_v<<<dim3(15, 16, 32), 256, 0, stream>>>(Vb, Vt);

  attn_softmax<<<dim3(32, 32), 512, 0, stream>>>(Qb, Kb, mask, P);

  // context[b] = P[b] . Vt[b]^T  : M=1024, N=960, K=1024, fp32 out
  gemm_nt<0, 0><<<dim3(8, 8, 32), 256, 0, stream>>>(
      P, Vt, nullptr, 1.0f, ctx, 1024, 1024, 960, 960, 32,
      (size_t)1048576, (size_t)1048576, (size_t)983040);

  hipMemsetAsync(pooled, 0, 32 * 960 * 4, stream);
  ln_pool<<<dim3(32, 32), 256, 0, stream>>>(ctx, x, mask, lng, lnb, pooled);
  mlp_head<<<32, 256, 0, stream>>>(pooled, mask, W1, b1, W2, b2, W3, b3, W4, b4, out);
}

// Round 2
// 676.545 us; speedup vs baseline: 1.4927x; 1.4927x over previous
//
#include <hip/hip_runtime.h>

// ---------------------------------------------------------------------------
// DeepProteinClassifier: x[32,1024,960] fp32, mask[32,1024] i32 ->
//   QKV proj -> attention -> +x, LN -> masked mean pool -> MLP -> [32,10] f32
// bf16 MFMA (16x16x32) everywhere big; fp32 epilogues.
// ---------------------------------------------------------------------------

#define DEVINL __device__ __forceinline__

typedef __attribute__((ext_vector_type(8))) short bf16x8;
typedef __attribute__((ext_vector_type(4))) float f32x4;
typedef __attribute__((ext_vector_type(4))) unsigned short u16x4;

DEVINL unsigned short f2bf(float f) {
  unsigned int u = __float_as_uint(f);
  u += 0x7FFFu + ((u >> 16) & 1u);  // round-to-nearest-even
  return (unsigned short)(u >> 16);
}

DEVINL void gload_lds16(const void* g, void* l) {
  __builtin_amdgcn_global_load_lds((const __attribute__((address_space(1))) unsigned int*)g,
                                   (__attribute__((address_space(3))) unsigned int*)l,
                                   16, 0, 0);
}

#define MFMA16(a, b, c) __builtin_amdgcn_mfma_f32_16x16x32_bf16((a), (b), (c), 0, 0, 0)

// ---------------------------------------------------------------------------
// cast W matrices [960x960] f32 -> bf16. grid (900,1,3), 4 elems/thread.
// ---------------------------------------------------------------------------
__global__ __launch_bounds__(256) void cast_w(
    const float* __restrict__ Wq, const float* __restrict__ Wk, const float* __restrict__ Wv,
    unsigned short* __restrict__ Wqb, unsigned short* __restrict__ Wkb,
    unsigned short* __restrict__ Wvb) {
  const int z = blockIdx.z;
  const float* src = (z == 0) ? Wq : (z == 1) ? Wk : Wv;
  unsigned short* dst = (z == 0) ? Wqb : (z == 1) ? Wkb : Wvb;
  const int i = (blockIdx.x * 256 + threadIdx.x) * 4;
  f32x4 v = *(const f32x4*)(src + i);
  u16x4 o;
  o[0] = f2bf(v[0]); o[1] = f2bf(v[1]); o[2] = f2bf(v[2]); o[3] = f2bf(v[3]);
  *(u16x4*)(dst + i) = o;
}

// ---------------------------------------------------------------------------
// cast x [32768x960] f32 -> bf16. grid 15360, 8 elems/thread.
// ---------------------------------------------------------------------------
__global__ __launch_bounds__(256) void cast_x(
    const float* __restrict__ x, unsigned short* __restrict__ xb) {
  const size_t i = ((size_t)blockIdx.x * 256 + threadIdx.x) * 8;
  f32x4 v0 = *(const f32x4*)(x + i);
  f32x4 v1 = *(const f32x4*)(x + i + 4);
  bf16x8 o;
  o[0] = (short)f2bf(v0[0]); o[1] = (short)f2bf(v0[1]);
  o[2] = (short)f2bf(v0[2]); o[3] = (short)f2bf(v0[3]);
  o[4] = (short)f2bf(v1[0]); o[5] = (short)f2bf(v1[1]);
  o[6] = (short)f2bf(v1[2]); o[7] = (short)f2bf(v1[3]);
  *(bf16x8*)(xb + i) = o;
}

// ---------------------------------------------------------------------------
// Pure-bf16 NT GEMM, 128x128 tile, BK=64, 4 waves (2x2), 64x64 out each.
// Both operands staged via global_load_lds (linear LDS dest); 128B LDS rows
// use a (row&7) slot-XOR swizzle applied on the GLOBAL source address and the
// LDS read address (rule: both-sides-or-neither).
// OUT_MODE: 0 = f32 direct; 1 = bf16 (acc+bias)*scale row-major;
//           2 = bf16 (acc+bias) written TRANSPOSED into Vt[b][col][row%1024].
// nbrows guards B-row staging (skip whole 8-row chunks past nbrows).
// ---------------------------------------------------------------------------
template <int OUT_MODE>
__global__ __launch_bounds__(256, 3) void gemm_nt(
    const unsigned short* __restrict__ Ap, const unsigned short* __restrict__ Bp,
    const float* __restrict__ bias, float scale, void* __restrict__ Op,
    int lda, int ldb, int ldo, int ncols, int nbrows, int ksteps,
    size_t aStride, size_t bStride, size_t oStride) {
  __shared__ unsigned short As[128 * 64];
  __shared__ unsigned short Bs[128 * 64];
  const int t = threadIdx.x, l = t & 63, w = t >> 6;
  const int wr = w >> 1, wc = w & 1;
  const int m0 = blockIdx.x * 128, n0 = blockIdx.y * 128;
  const int bz = blockIdx.z;
  const unsigned short* A = Ap + (size_t)bz * aStride;
  const unsigned short* B = Bp + (size_t)bz * bStride;
  const int lr = l >> 3, sg0 = l & 7;  // 8 rows x 8 slots(16B) per 1KB issue
  f32x4 acc[4][4] = {};

  for (int kk = 0; kk < ksteps; ++kk) {
    const int d0 = kk * 64;
    __syncthreads();
#pragma unroll
    for (int i = 0; i < 4; ++i) {
      const int br = w * 32 + i * 8;
      const int ar = br + lr;
      const int sg = sg0 ^ (ar & 7);
      gload_lds16(A + (size_t)(m0 + ar) * lda + d0 + sg * 8, (char*)As + (size_t)br * 128);
      if (n0 + br + 8 <= nbrows)
        gload_lds16(B + (size_t)(n0 + ar) * ldb + d0 + sg * 8, (char*)Bs + (size_t)br * 128);
    }
    __syncthreads();
    bf16x8 aF[2][4], bF[2][4];
#pragma unroll
    for (int h = 0; h < 2; ++h)
#pragma unroll
      for (int i = 0; i < 4; ++i) {
        const int rowA = 64 * wr + 16 * i + (l & 15);
        aF[h][i] = *(const bf16x8*)(As + (size_t)rowA * 64 +
                                    (size_t)(((h << 2) | (l >> 4)) ^ (rowA & 7)) * 8);
        const int rowB = 64 * wc + 16 * i + (l & 15);
        bF[h][i] = *(const bf16x8*)(Bs + (size_t)rowB * 64 +
                                    (size_t)(((h << 2) | (l >> 4)) ^ (rowB & 7)) * 8);
      }
#pragma unroll
    for (int h = 0; h < 2; ++h)
#pragma unroll
      for (int i = 0; i < 4; ++i)
#pragma unroll
        for (int j = 0; j < 4; ++j) acc[i][j] = MFMA16(aF[h][i], bF[h][j], acc[i][j]);
  }

  // epilogue: C/D layout col = lane&15, row = (lane>>4)*4 + reg
#pragma unroll
  for (int j = 0; j < 4; ++j) {
    const int col = n0 + 64 * wc + 16 * j + (l & 15);
    if (col >= ncols) continue;
    const float bv = (OUT_MODE != 0) ? bias[col] : 0.0f;
#pragma unroll
    for (int i = 0; i < 4; ++i)
#pragma unroll
      for (int r = 0; r < 4; ++r) {
        const int row = m0 + 64 * wr + 16 * i + 4 * (l >> 4) + r;
        const float v = acc[i][j][r];
        if (OUT_MODE == 0) {
          ((float*)Op)[(size_t)bz * oStride + (size_t)row * ldo + col] = v;
        } else if (OUT_MODE == 1) {
          ((unsigned short*)Op)[(size_t)bz * oStride + (size_t)row * ldo + col] =
              f2bf((v + bv) * scale);
        } else {  // transposed V: Vt[b][col][s], b=row>>10, s=row&1023
          ((unsigned short*)Op)[((size_t)(row >> 10) << 20) + ((size_t)col << 10) + (row & 1023)] =
              f2bf((v + bv) * scale);
        }
      }
  }
}

// ---------------------------------------------------------------------------
// Fused scores + masked softmax, v2.
// Block = 64 q-rows x full 1024 k for one b; 8 waves, wave w owns k-cols
// [128w,128w+128). K slab (1024x32) + Q slab (64x32) double-buffered in LDS,
// staged via global_load_lds with (row>>1)&3 slot-XOR source swizzle.
// 2-phase pipeline: issue stage(kk+1) before compute(kk), one barrier per kk.
// XCD-chunked block mapping: dispatch f -> XCD f%8 handles b in [4*(f%8), +4).
// ---------------------------------------------------------------------------
__global__ __launch_bounds__(512, 2) void attn_softmax(
    const unsigned short* __restrict__ Qb, const unsigned short* __restrict__ Kb,
    const int* __restrict__ mask, unsigned short* __restrict__ P) {
  __shared__ unsigned short Ks[2][1024 * 32];
  __shared__ unsigned short Qs[2][64 * 32];
  __shared__ float red[2][8][64];
  const int t = threadIdx.x, l = t & 63, w = t >> 6;
  const int flat = blockIdx.x;
  const int b = (flat & 7) * 4 + ((flat >> 3) >> 4);
  const int q0 = ((flat >> 3) & 15) * 64;
  const int lq = l & 15, lh = l >> 4;
  const size_t kbase = (size_t)b * 1024 * 960;
  const size_t qbase = ((size_t)b * 1024 + q0) * 960;
  const int lr = l >> 2, sg0 = l & 3;  // 16 rows x 4 slots(16B) per 1KB issue

#define STAGE(kkv, bufv)                                                        \
  {                                                                             \
    const int d0_ = (kkv) * 32;                                                 \
    _Pragma("unroll") for (int i_ = 0; i_ < 8; ++i_) {                          \
      const int br_ = i_ * 128 + w * 16;                                        \
      const int kr_ = br_ + lr;                                                 \
      const int sg_ = sg0 ^ ((kr_ >> 1) & 3);                                   \
      gload_lds16(Kb + kbase + (size_t)kr_ * 960 + d0_ + sg_ * 8,               \
                  (char*)Ks[(bufv)] + (size_t)br_ * 64);                        \
    }                                                                           \
    if (w < 4) {                                                                \
      const int qr_ = w * 16 + lr;                                              \
      const int sg_ = sg0 ^ ((qr_ >> 1) & 3);                                   \
      gload_lds16(Qb + qbase + (size_t)qr_ * 960 + d0_ + sg_ * 8,               \
                  (char*)Qs[(bufv)] + (size_t)(w * 16) * 64);                   \
    }                                                                           \
  }

  f32x4 acc[4][8] = {};
  STAGE(0, 0);
  __syncthreads();
  int buf = 0;
  for (int kk = 0; kk < 30; ++kk) {
    if (kk < 29) STAGE(kk + 1, buf ^ 1);
    bf16x8 aF[4], bF[8];
#pragma unroll
    for (int i = 0; i < 4; ++i) {
      const int qr = 16 * i + lq;
      aF[i] = *(const bf16x8*)(Qs[buf] + qr * 32 + (lh ^ ((qr >> 1) & 3)) * 8);
    }
#pragma unroll
    for (int j = 0; j < 8; ++j) {
      const int kr = 128 * w + 16 * j + lq;
      bF[j] = *(const bf16x8*)(Ks[buf] + kr * 32 + (lh ^ ((kr >> 1) & 3)) * 8);
    }
#pragma unroll
    for (int i = 0; i < 4; ++i)
#pragma unroll
      for (int j = 0; j < 8; ++j) acc[i][j] = MFMA16(aF[i], bF[j], acc[i][j]);
    __syncthreads();  // drains vmcnt(0): stage(kk+1) landed; readers of buf done
    buf ^= 1;
  }
#undef STAGE

  // mask -> -1e9
#pragma unroll
  for (int j = 0; j < 8; ++j) {
    const int k = 128 * w + 16 * j + lq;
    if (mask[b * 1024 + k] == 0) {
#pragma unroll
      for (int i = 0; i < 4; ++i)
#pragma unroll
        for (int r = 0; r < 4; ++r) acc[i][j][r] = -1e9f;
    }
  }

  // row max: over j in-lane, over 16 col-lanes via shfl, over 8 waves via LDS
  float rmax[4][4];
#pragma unroll
  for (int i = 0; i < 4; ++i)
#pragma unroll
    for (int r = 0; r < 4; ++r) {
      float m = acc[i][0][r];
#pragma unroll
      for (int j = 1; j < 8; ++j) m = fmaxf(m, acc[i][j][r]);
      m = fmaxf(m, __shfl_xor(m, 1));
      m = fmaxf(m, __shfl_xor(m, 2));
      m = fmaxf(m, __shfl_xor(m, 4));
      m = fmaxf(m, __shfl_xor(m, 8));
      rmax[i][r] = m;
    }
  if (lq == 0) {
#pragma unroll
    for (int i = 0; i < 4; ++i)
#pragma unroll
      for (int r = 0; r < 4; ++r) red[0][w][16 * i + 4 * lh + r] = rmax[i][r];
  }
  __syncthreads();
#pragma unroll
  for (int i = 0; i < 4; ++i)
#pragma unroll
    for (int r = 0; r < 4; ++r) {
      const int rowi = 16 * i + 4 * lh + r;
      float m = red[0][0][rowi];
#pragma unroll
      for (int w2 = 1; w2 < 8; ++w2) m = fmaxf(m, red[0][w2][rowi]);
      rmax[i][r] = m;
    }

  float rsum[4][4];
#pragma unroll
  for (int i = 0; i < 4; ++i)
#pragma unroll
    for (int r = 0; r < 4; ++r) {
      float s = 0.f;
#pragma unroll
      for (int j = 0; j < 8; ++j) {
        const float e = __expf(acc[i][j][r] - rmax[i][r]);
        acc[i][j][r] = e;
        s += e;
      }
      s += __shfl_xor(s, 1); s += __shfl_xor(s, 2);
      s += __shfl_xor(s, 4); s += __shfl_xor(s, 8);
      rsum[i][r] = s;
    }
  if (lq == 0) {
#pragma unroll
    for (int i = 0; i < 4; ++i)
#pragma unroll
      for (int r = 0; r < 4; ++r) red[1][w][16 * i + 4 * lh + r] = rsum[i][r];
  }
  __syncthreads();

  const size_t pb = ((size_t)b << 20) + (size_t)q0 * 1024;
#pragma unroll
  for (int i = 0; i < 4; ++i)
#pragma unroll
    for (int r = 0; r < 4; ++r) {
      const int rowi = 16 * i + 4 * lh + r;
      float s = 0.f;
#pragma unroll
      for (int w2 = 0; w2 < 8; ++w2) s += red[1][w2][rowi];
      const float inv = 1.0f / s;
#pragma unroll
      for (int j = 0; j < 8; ++j) {
        const int col = 128 * w + 16 * j + lq;
        P[pb + (size_t)rowi * 1024 + col] = f2bf(acc[i][j][r] * inv);
      }
    }
}

// ---------------------------------------------------------------------------
// h = ctx + x; LayerNorm(h)*g+b; pooled[b,d] += y for masked rows (atomics).
// grid (32 s-chunks, 32 b), block 256 (wave-per-row, 8 rows/wave).
// ---------------------------------------------------------------------------
__global__ __launch_bounds__(256) void ln_pool(
    const float* __restrict__ ctx, const float* __restrict__ x, const int* __restrict__ mask,
    const float* __restrict__ g, const float* __restrict__ bta, float* __restrict__ pooled) {
  const int b = blockIdx.y, chunk = blockIdx.x;
  const int w = threadIdx.x >> 6, l = threadIdx.x & 63;
  f32x4 gc[4], bc[4];
#pragma unroll
  for (int c = 0; c < 4; ++c) {
    const int i4 = c * 64 + l;
    if (i4 < 240) {
      gc[c] = *(const f32x4*)(g + i4 * 4);
      bc[c] = *(const f32x4*)(bta + i4 * 4);
    }
  }
  f32x4 accp[4] = {};
  for (int rr = 0; rr < 8; ++rr) {
    const int s = chunk * 32 + w * 8 + rr;
    if (mask[b * 1024 + s] == 0) continue;
    const size_t base = ((size_t)b * 1024 + s) * 960;
    f32x4 h[4];
    float part = 0.f;
#pragma unroll
    for (int c = 0; c < 4; ++c) {
      const int i4 = c * 64 + l;
      if (i4 < 240) {
        f32x4 cv = *(const f32x4*)(ctx + base + (size_t)i4 * 4);
        f32x4 xv = *(const f32x4*)(x + base + (size_t)i4 * 4);
        h[c] = cv + xv;
        part += h[c][0] + h[c][1] + h[c][2] + h[c][3];
      } else {
        h[c] = 0;
      }
    }
#pragma unroll
    for (int o = 1; o < 64; o <<= 1) part += __shfl_xor(part, o);
    const float mu = part * (1.0f / 960.0f);
    float p2 = 0.f;
#pragma unroll
    for (int c = 0; c < 4; ++c) {
      if (c * 64 + l < 240) {
#pragma unroll
        for (int k2 = 0; k2 < 4; ++k2) {
          const float d = h[c][k2] - mu;
          p2 += d * d;
        }
      }
    }
#pragma unroll
    for (int o = 1; o < 64; o <<= 1) p2 += __shfl_xor(p2, o);
    const float rs = rsqrtf(p2 * (1.0f / 960.0f) + 1e-5f);
#pragma unroll
    for (int c = 0; c < 4; ++c) {
      if (c * 64 + l < 240) {
#pragma unroll
        for (int k2 = 0; k2 < 4; ++k2)
          accp[c][k2] += (h[c][k2] - mu) * rs * gc[c][k2] + bc[c][k2];
      }
    }
  }
#pragma unroll
  for (int c = 0; c < 4; ++c) {
    const int i4 = c * 64 + l;
    if (i4 < 240) {
#pragma unroll
      for (int k2 = 0; k2 < 4; ++k2) atomicAdd(&pooled[b * 960 + i4 * 4 + k2], accp[c][k2]);
    }
  }
}

// ---------------------------------------------------------------------------
// pooled/count -> 960-512-256-128-10 MLP fp32. One block per batch row.
// ---------------------------------------------------------------------------
__global__ __launch_bounds__(256) void mlp_head(
    const float* __restrict__ pooled, const int* __restrict__ mask,
    const float* __restrict__ W1, const float* __restrict__ b1,
    const float* __restrict__ W2, const float* __restrict__ b2,
    const float* __restrict__ W3, const float* __restrict__ b3,
    const float* __restrict__ W4, const float* __restrict__ b4, float* __restrict__ out) {
  __shared__ float h0[960], h1[512], h2[256], h3[128];
  __shared__ float csh[4];
  const int b = blockIdx.x, t = threadIdx.x;
  int cnt = 0;
  for (int s = t; s < 1024; s += 256) cnt += (mask[b * 1024 + s] != 0) ? 1 : 0;
#pragma unroll
  for (int o = 1; o < 64; o <<= 1) cnt += __shfl_xor(cnt, o);
  if ((t & 63) == 0) csh[t >> 6] = (float)cnt;
  __syncthreads();
  const float inv = 1.0f / fmaxf(csh[0] + csh[1] + csh[2] + csh[3], 1e-9f);
  for (int d = t; d < 960; d += 256) h0[d] = pooled[b * 960 + d] * inv;
  __syncthreads();
  for (int o = t; o < 512; o += 256) {
    float a = b1[o];
    const float* wr = W1 + (size_t)o * 960;
    for (int k = 0; k < 960; k += 4) {
      f32x4 wv = *(const f32x4*)(wr + k);
      f32x4 hv = *(const f32x4*)(h0 + k);
      a += wv[0] * hv[0] + wv[1] * hv[1] + wv[2] * hv[2] + wv[3] * hv[3];
    }
    h1[o] = fmaxf(a, 0.f);
  }
  __syncthreads();
  {
    float a = b2[t];
    const float* wr = W2 + (size_t)t * 512;
    for (int k = 0; k < 512; k += 4) {
      f32x4 wv = *(const f32x4*)(wr + k);
      f32x4 hv = *(const f32x4*)(h1 + k);
      a += wv[0] * hv[0] + wv[1] * hv[1] + wv[2] * hv[2] + wv[3] * hv[3];
    }
    h2[t] = fmaxf(a, 0.f);
  }
  __syncthreads();
  if (t < 128) {
    float a = b3[t];
    const float* wr = W3 + (size_t)t * 256;
    for (int k = 0; k < 256; k += 4) {
      f32x4 wv = *(const f32x4*)(wr + k);
      f32x4 hv = *(const f32x4*)(h2 + k);
      a += wv[0] * hv[0] + wv[1] * hv[1] + wv[2] * hv[2] + wv[3] * hv[3];
    }
    h3[t] = fmaxf(a, 0.f);
  }
  __syncthreads();
  if (t < 10) {
    float a = b4[t];
    const float* wr = W4 + (size_t)t * 128;
    for (int k = 0; k < 128; ++k) a += wr[k] * h3[k];
    out[b * 10 + t] = a;
  }
}

// ---------------------------------------------------------------------------
// Workspace (bytes):
//   [0,          67108864)  P   bf16 [32][1024][1024]
//   [67108864,  130023424)  xb  bf16 [32768][960]          (dead after V gemm)
//   [130023424, 192937984)  Qb  bf16 [32768][960]          (dead after attn)
//   [192937984, 255852544)  Kb  bf16                        (dead after attn)
//   [192937984, 260046848)  Vt  bf16 [32][1024][1024] (over Kb, after attn)
//   [67108864,  192937984)  ctx f32 [32768][960]   (over xb+Qb, after V gemm)
//   [260046848, 260169728)  pooled f32 [32][960]
//   [260169728, 265699328)  Wq/Wk/Wv bf16 [960*960] each
// ---------------------------------------------------------------------------
extern "C" void kernel_launch(void* const* d_in, const int* in_sizes, int n_in,
                              void* d_out, int out_size, void* d_ws, size_t ws_size,
                              hipStream_t stream) {
  (void)in_sizes; (void)n_in; (void)out_size; (void)ws_size;
  const float* x    = (const float*)d_in[0];
  const int*   mask = (const int*)d_in[1];
  const float* Wq   = (const float*)d_in[2];
  const float* bq   = (const float*)d_in[3];
  const float* Wk   = (const float*)d_in[4];
  const float* bk   = (const float*)d_in[5];
  const float* Wv   = (const float*)d_in[6];
  const float* bv   = (const float*)d_in[7];
  const float* lng  = (const float*)d_in[8];
  const float* lnb  = (const float*)d_in[9];
  const float* W1   = (const float*)d_in[10];
  const float* b1   = (const float*)d_in[11];
  const float* W2   = (const float*)d_in[12];
  const float* b2   = (const float*)d_in[13];
  const float* W3   = (const float*)d_in[14];
  const float* b3   = (const float*)d_in[15];
  const float* W4   = (const float*)d_in[16];
  const float* b4   = (const float*)d_in[17];
  float* out = (float*)d_out;

  char* ws = (char*)d_ws;
  unsigned short* P      = (unsigned short*)(ws);
  unsigned short* xb     = (unsigned short*)(ws + 67108864);
  unsigned short* Qb     = (unsigned short*)(ws + 130023424);
  unsigned short* Kb     = (unsigned short*)(ws + 192937984);
  unsigned short* Vt     = (unsigned short*)(ws + 192937984);
  float*          ctx    = (float*)(ws + 67108864);
  float*          pooled = (float*)(ws + 260046848);
  unsigned short* Wqb    = (unsigned short*)(ws + 260169728);
  unsigned short* Wkb    = Wqb + 921600;
  unsigned short* Wvb    = Wkb + 921600;

  const float scaleQ = 0.0322748612183951f;  // 1/sqrt(960)

  cast_w<<<dim3(900, 1, 3), 256, 0, stream>>>(Wq, Wk, Wv, Wqb, Wkb, Wvb);
  cast_x<<<15360, 256, 0, stream>>>(x, xb);

  // Q,K projections: [32768x960] = xb . W^T (+bias; Q pre-scaled)
  gemm_nt<1><<<dim3(256, 8, 1), 256, 0, stream>>>(
      xb, Wqb, bq, scaleQ, Qb, 960, 960, 960, 960, 960, 15, 0, 0, 0);
  gemm_nt<1><<<dim3(256, 8, 1), 256, 0, stream>>>(
      xb, Wkb, bk, 1.0f, Kb, 960, 960, 960, 960, 960, 15, 0, 0, 0);

  attn_softmax<<<512, 512, 0, stream>>>(Qb, Kb, mask, P);

  // V projection, epilogue writes transposed into Vt (over dead Kb)
  gemm_nt<2><<<dim3(256, 8, 1), 256, 0, stream>>>(
      xb, Wvb, bv, 1.0f, Vt, 960, 960, 0, 960, 960, 15, 0, 0, 0);

  // context[b] = P[b] . Vt[b]^T : M=1024, N=960, K=1024, f32 out (over xb+Qb)
  gemm_nt<0><<<dim3(8, 8, 32), 256, 0, stream>>>(
      P, Vt, nullptr, 1.0f, ctx, 1024, 1024, 960, 960, 960, 16,
      (size_t)1048576, (size_t)1048576, (size_t)983040);

  hipMemsetAsync(pooled, 0, 32 * 960 * 4, stream);
  ln_pool<<<dim3(32, 32), 256, 0, stream>>>(ctx, x, mask, lng, lnb, pooled);
  mlp_head<<<32, 256, 0, stream>>>(pooled, mask, W1, b1, W2, b2, W3, b3, W4, b4, out);
}